// Round 5
// baseline (313.295 us; speedup 1.0000x reference)
//
#include <hip/hip_runtime.h>
#include <cstddef>

#define LQ 1024
#define DM 128
#define DI 256
#define DSN 16
#define NB 8
#define ROWS (NB*LQ)
#define EPSF 1e-5f
#define CHUNK 32
#define NCHUNK (LQ/CHUNK)

typedef _Float16 f16;
typedef __attribute__((ext_vector_type(8))) _Float16 f16x8;
typedef __attribute__((ext_vector_type(4))) _Float16 f16x4;
typedef __attribute__((ext_vector_type(4))) float f32x4;

static __device__ __forceinline__ float sigmoid_f(float x) { return 1.f/(1.f+__expf(-x)); }
static __device__ __forceinline__ float softplus_f(float x) {
  return (x > 20.f) ? x : log1pf(__expf(x));
}

// ---------------- one-shot fp32 -> fp16 conversion of all three weight sets ----------------
__global__ __launch_bounds__(256) void cvt_all(
    const float* __restrict__ a, const float* __restrict__ bsrc, const float* __restrict__ csrc,
    f16* __restrict__ oa, f16* __restrict__ ob, f16* __restrict__ oc)
{
  int i = blockIdx.x*256 + threadIdx.x;
  const int na = (4*2*DI*DM)/4;   // 65536 float4 groups
  const int nb = (4*40*DI)/4;     // 10240
  const int nc = (4*DM*DI)/4;     // 32768
  const float* s; f16* o; int k;
  if (i < na)            { s = a;    o = oa; k = i; }
  else if (i < na+nb)    { s = bsrc; o = ob; k = i - na; }
  else if (i < na+nb+nc) { s = csrc; o = oc; k = i - na - nb; }
  else return;
  float4 v = ((const float4*)s)[k];
  f16x4 r; r.x=(f16)v.x; r.y=(f16)v.y; r.z=(f16)v.z; r.w=(f16)v.w;
  ((f16x4*)o)[k] = r;
}

// ============ K_A: rmsnorm + in_proj(x-half, with conv halo) + conv/silu + x_proj + scan p1 ============
// block = (batch, 32-step chunk), 256 threads = 4 waves
__global__ __launch_bounds__(256) void layer_front(
    const float* __restrict__ src, const float* __restrict__ nw,
    const f16* __restrict__ Win,                      // [512][128] f16 (x-half rows 0..255)
    const float* __restrict__ cw, const float* __restrict__ cb,
    const f16* __restrict__ xpw,                      // [40][256] f16
    const float* __restrict__ A_log,
    const float* __restrict__ dtw, const float* __restrict__ dtb,
    f16* __restrict__ xs_out, float* __restrict__ dbc_out,
    float* __restrict__ S, float* __restrict__ sumdl_out)
{
  __shared__ __align__(16) f16 Ah[48][136];     // rmsnorm'd rows t0-3 .. t0+31 (rows 35..47 zero)
  __shared__ __align__(16) f16 sXc[48][264];    // in_proj x-half output (conv input)
  __shared__ __align__(16) f16 sXs[32][264];    // conv+silu output
  __shared__ __align__(16) float sDbc[32][40];
  const int bc = blockIdx.x;
  const int b = bc >> 5, ck = bc & (NCHUNK-1);
  const int t0 = ck*CHUNK;
  const int tid = threadIdx.x;

  // --- stage A with fused rmsnorm: 4 lanes per row ---
  {
    const int r = tid >> 2;              // 0..63
    const int seg = (tid & 3) * 32;
    float4 v[8];
    float ss = 0.f;
    const bool valid = (r < 35) && (ck > 0 || r >= 3);
    if (valid) {
      const float* hr = src + (size_t)(b*LQ + t0 - 3 + r)*DM + seg;
      #pragma unroll
      for (int j = 0; j < 8; ++j) {
        v[j] = *(const float4*)(hr + j*4);
        ss += v[j].x*v[j].x + v[j].y*v[j].y + v[j].z*v[j].z + v[j].w*v[j].w;
      }
    }
    ss += __shfl_xor(ss, 1);
    ss += __shfl_xor(ss, 2);
    if (r < 48) {
      if (valid) {
        const float sc = rsqrtf(ss*(1.f/128.f) + EPSF);
        #pragma unroll
        for (int j = 0; j < 8; ++j) {
          float4 wv = *(const float4*)(nw + seg + j*4);
          f16x4 o;
          o.x=(f16)(v[j].x*sc*wv.x); o.y=(f16)(v[j].y*sc*wv.y);
          o.z=(f16)(v[j].z*sc*wv.z); o.w=(f16)(v[j].w*sc*wv.w);
          *(f16x4*)&Ah[r][seg + j*4] = o;
        }
      } else {
        #pragma unroll
        for (int j = 0; j < 8; ++j)
          *(f16x4*)&Ah[r][seg + j*4] = (f16x4){0,0,0,0};
      }
    }
  }
  __syncthreads();

  const int l = tid & 63, w = tid >> 6;
  const int fr = l & 15, kg = l >> 4;

  // --- in_proj x-half MFMA: xc[48][256] = Ah @ Win_x^T (wave w -> cols w*64..w*64+63) ---
  {
    f32x4 acc[3][4];
    #pragma unroll
    for (int m = 0; m < 3; ++m)
      #pragma unroll
      for (int n = 0; n < 4; ++n)
        acc[m][n] = (f32x4){0.f,0.f,0.f,0.f};
    #pragma unroll
    for (int s = 0; s < 4; ++s) {
      f16x8 af[3];
      #pragma unroll
      for (int m = 0; m < 3; ++m)
        af[m] = *(const f16x8*)&Ah[m*16 + fr][s*32 + kg*8];
      #pragma unroll
      for (int n = 0; n < 4; ++n) {
        f16x8 bfv = *(const f16x8*)(Win + (size_t)(w*64 + n*16 + fr)*DM + s*32 + kg*8);
        #pragma unroll
        for (int m = 0; m < 3; ++m)
          acc[m][n] = __builtin_amdgcn_mfma_f32_16x16x32_f16(af[m], bfv, acc[m][n], 0, 0, 0);
      }
    }
    #pragma unroll
    for (int m = 0; m < 3; ++m)
      #pragma unroll
      for (int n = 0; n < 4; ++n) {
        const int col = w*64 + n*16 + fr;
        #pragma unroll
        for (int j = 0; j < 4; ++j)
          sXc[m*16 + kg*4 + j][col] = (f16)acc[m][n][j];
      }
  }
  __syncthreads();

  // --- conv + silu (thread = channel); conv out t uses sXc rows t..t+3 ---
  {
    const int d = tid;
    const float4 cwv = *(const float4*)(cw + d*4);
    const float bias = cb[d];
    #pragma unroll 4
    for (int t = 0; t < CHUNK; ++t) {
      float a = bias + (float)sXc[t][d]*cwv.x + (float)sXc[t+1][d]*cwv.y
                     + (float)sXc[t+2][d]*cwv.z + (float)sXc[t+3][d]*cwv.w;
      float sv = a * sigmoid_f(a);
      f16 s16 = (f16)sv;
      sXs[t][d] = s16;
      xs_out[(size_t)(b*LQ + t0 + t)*DI + d] = s16;
    }
  }
  __syncthreads();

  // --- x_proj MFMA: dbc[32][40] = xs @ xpw^T (waves 0..2, 16 cols each) ---
  if (w < 3) {
    f32x4 acc[2];
    acc[0] = (f32x4){0.f,0.f,0.f,0.f};
    acc[1] = (f32x4){0.f,0.f,0.f,0.f};
    const int wrow = w*16 + fr;
    #pragma unroll
    for (int s = 0; s < 8; ++s) {
      f16x8 bfv = (f16x8){0,0,0,0,0,0,0,0};
      if (wrow < 40) bfv = *(const f16x8*)(xpw + (size_t)wrow*DI + s*32 + kg*8);
      #pragma unroll
      for (int m = 0; m < 2; ++m) {
        f16x8 afv = *(const f16x8*)&sXs[m*16 + fr][s*32 + kg*8];
        acc[m] = __builtin_amdgcn_mfma_f32_16x16x32_f16(afv, bfv, acc[m], 0, 0, 0);
      }
    }
    if (wrow < 40) {
      #pragma unroll
      for (int m = 0; m < 2; ++m)
        #pragma unroll
        for (int j = 0; j < 4; ++j) {
          int row = m*16 + kg*4 + j;
          sDbc[row][wrow] = acc[m][j];
          dbc_out[(size_t)(b*LQ + t0 + row)*40 + wrow] = acc[m][j];
        }
    }
  }
  __syncthreads();

  // --- scan phase 1 (thread = channel): dt fused; emit chunk-final state S + sum(delta) ---
  {
    const int d = tid;
    float A[16];
    #pragma unroll
    for (int n = 0; n < 16; ++n) A[n] = -__expf(A_log[d*16+n]);
    const float4 dw0 = *(const float4*)(dtw + d*8);
    const float4 dw1 = *(const float4*)(dtw + d*8 + 4);
    const float bt = dtb[d];
    float h[16] = {};
    float sdl = 0.f;
    for (int t = 0; t < CHUNK; ++t) {
      float xa = bt + sDbc[t][0]*dw0.x + sDbc[t][1]*dw0.y + sDbc[t][2]*dw0.z + sDbc[t][3]*dw0.w
                    + sDbc[t][4]*dw1.x + sDbc[t][5]*dw1.y + sDbc[t][6]*dw1.z + sDbc[t][7]*dw1.w;
      float dl = softplus_f(xa);
      float uu = (float)sXs[t][d];
      float du = dl*uu;
      sdl += dl;
      #pragma unroll
      for (int n = 0; n < 16; ++n)
        h[n] = __expf(dl*A[n])*h[n] + du*sDbc[t][8+n];
    }
    float* Sp = S + ((size_t)bc*DI + d)*16;
    #pragma unroll
    for (int n = 0; n < 16; n += 4)
      *(float4*)(Sp+n) = make_float4(h[n],h[n+1],h[n+2],h[n+3]);
    sumdl_out[(size_t)bc*DI + d] = sdl;
  }
}

// ============ K_C: rmsnorm + in_proj(z-half) + chunk-prefix + scan p3 + gate + out_proj + residual ============
__global__ __launch_bounds__(256) void layer_back(
    const float* __restrict__ src, const float* __restrict__ nw,
    const f16* __restrict__ Win,                      // full [512][128]; z rows 256..511
    const f16* __restrict__ xs, const float* __restrict__ dbc,
    const float* __restrict__ A_log,
    const float* __restrict__ dtw, const float* __restrict__ dtb,
    const float* __restrict__ Dp, const float* __restrict__ S,
    const float* __restrict__ sumdl, const f16* __restrict__ Wo,
    float* __restrict__ hout)
{
  __shared__ __align__(16) f16 Ah[32][136];
  __shared__ __align__(16) f16 sZ[32][264];
  __shared__ __align__(16) f16 sY[32][264];
  __shared__ float sB[CHUNK][16];
  __shared__ float sC[CHUNK][16];
  __shared__ float sDL[CHUNK][8];
  const int bc = blockIdx.x;
  const int b = bc >> 5, ck = bc & (NCHUNK-1);
  const int t0 = ck*CHUNK;
  const int tid = threadIdx.x;

  // --- stage A with fused rmsnorm: 8 lanes per row ---
  {
    const int r = tid >> 3;              // 0..31
    const int seg = (tid & 7) * 16;
    const float* hr = src + (size_t)(b*LQ + t0 + r)*DM + seg;
    float4 v[4];
    float ss = 0.f;
    #pragma unroll
    for (int j = 0; j < 4; ++j) {
      v[j] = *(const float4*)(hr + j*4);
      ss += v[j].x*v[j].x + v[j].y*v[j].y + v[j].z*v[j].z + v[j].w*v[j].w;
    }
    ss += __shfl_xor(ss, 1);
    ss += __shfl_xor(ss, 2);
    ss += __shfl_xor(ss, 4);
    const float sc = rsqrtf(ss*(1.f/128.f) + EPSF);
    #pragma unroll
    for (int j = 0; j < 4; ++j) {
      float4 wv = *(const float4*)(nw + seg + j*4);
      f16x4 o;
      o.x=(f16)(v[j].x*sc*wv.x); o.y=(f16)(v[j].y*sc*wv.y);
      o.z=(f16)(v[j].z*sc*wv.z); o.w=(f16)(v[j].w*sc*wv.w);
      *(f16x4*)&Ah[r][seg + j*4] = o;
    }
  }
  // --- stage B/C/dlt from dbc ---
  for (int e = tid; e < CHUNK*16; e += 256) {
    int t = e >> 4, n = e & 15;
    size_t r = (size_t)(b*LQ + t0 + t)*40;
    sB[t][n] = dbc[r + 8 + n];
    sC[t][n] = dbc[r + 24 + n];
  }
  for (int e = tid; e < CHUNK*8; e += 256) {
    int t = e >> 3, j = e & 7;
    sDL[t][j] = dbc[(size_t)(b*LQ + t0 + t)*40 + j];
  }
  __syncthreads();

  const int l = tid & 63, w = tid >> 6;
  const int fr = l & 15, kg = l >> 4;

  // --- in_proj z-half MFMA: z[32][256] = Ah @ Win_z^T ---
  {
    f32x4 acc[2][4];
    #pragma unroll
    for (int m = 0; m < 2; ++m)
      #pragma unroll
      for (int n = 0; n < 4; ++n)
        acc[m][n] = (f32x4){0.f,0.f,0.f,0.f};
    #pragma unroll
    for (int s = 0; s < 4; ++s) {
      f16x8 af[2];
      #pragma unroll
      for (int m = 0; m < 2; ++m)
        af[m] = *(const f16x8*)&Ah[m*16 + fr][s*32 + kg*8];
      #pragma unroll
      for (int n = 0; n < 4; ++n) {
        f16x8 bfv = *(const f16x8*)(Win + (size_t)(DI + w*64 + n*16 + fr)*DM + s*32 + kg*8);
        #pragma unroll
        for (int m = 0; m < 2; ++m)
          acc[m][n] = __builtin_amdgcn_mfma_f32_16x16x32_f16(af[m], bfv, acc[m][n], 0, 0, 0);
      }
    }
    #pragma unroll
    for (int m = 0; m < 2; ++m)
      #pragma unroll
      for (int n = 0; n < 4; ++n) {
        const int col = w*64 + n*16 + fr;
        #pragma unroll
        for (int j = 0; j < 4; ++j)
          sZ[m*16 + kg*4 + j][col] = (f16)acc[m][n][j];
      }
  }

  // --- per-thread constants + chunk-prefix Hinit (register-only; replaces scan_p2) ---
  const int d = tid;
  float A[16];
  #pragma unroll
  for (int n = 0; n < 16; ++n) A[n] = -__expf(A_log[d*16+n]);
  float h[16] = {};
  for (int c = 0; c < ck; ++c) {
    float sdl = sumdl[(size_t)(b*NCHUNK + c)*DI + d];
    const float* Sp = S + ((size_t)(b*NCHUNK + c)*DI + d)*16;
    #pragma unroll
    for (int n = 0; n < 16; n += 4) {
      float4 sv = *(const float4*)(Sp + n);
      h[n]   = __expf(A[n]  *sdl)*h[n]   + sv.x;
      h[n+1] = __expf(A[n+1]*sdl)*h[n+1] + sv.y;
      h[n+2] = __expf(A[n+2]*sdl)*h[n+2] + sv.z;
      h[n+3] = __expf(A[n+3]*sdl)*h[n+3] + sv.w;
    }
  }
  const float4 dw0 = *(const float4*)(dtw + d*8);
  const float4 dw1 = *(const float4*)(dtw + d*8 + 4);
  const float bt = dtb[d];
  const float Dv = Dp[d];
  __syncthreads();

  // --- scan phase 3 + gate -> sY ---
  {
    const size_t ubase = (size_t)(b*LQ + t0)*DI + d;
    for (int t = 0; t < CHUNK; ++t) {
      float xa = bt + sDL[t][0]*dw0.x + sDL[t][1]*dw0.y + sDL[t][2]*dw0.z + sDL[t][3]*dw0.w
                    + sDL[t][4]*dw1.x + sDL[t][5]*dw1.y + sDL[t][6]*dw1.z + sDL[t][7]*dw1.w;
      float dl = softplus_f(xa);
      float uu = (float)xs[ubase + (size_t)t*DI];
      float du = dl*uu;
      float acc = uu*Dv;
      #pragma unroll
      for (int n = 0; n < 16; ++n) {
        h[n] = __expf(dl*A[n])*h[n] + du*sB[t][n];
        acc += h[n]*sC[t][n];
      }
      float res = (float)sZ[t][d];
      sY[t][d] = (f16)(acc * (res * sigmoid_f(res)));
    }
  }
  __syncthreads();

  // --- out_proj GEMM: y(32x256) @ Wo(128x256)^T + residual ---
  {
    f16x8 bf[2][8];
    #pragma unroll
    for (int n = 0; n < 2; ++n)
      #pragma unroll
      for (int s = 0; s < 8; ++s)
        bf[n][s] = *(const f16x8*)(Wo + (size_t)(w*32 + n*16 + fr)*DI + s*32 + kg*8);
    f32x4 acc[2][2];
    #pragma unroll
    for (int m = 0; m < 2; ++m)
      #pragma unroll
      for (int n = 0; n < 2; ++n)
        acc[m][n] = (f32x4){0.f,0.f,0.f,0.f};
    #pragma unroll
    for (int s = 0; s < 8; ++s)
      #pragma unroll
      for (int m = 0; m < 2; ++m) {
        f16x8 afv = *(const f16x8*)&sY[m*16 + fr][s*32 + kg*8];
        #pragma unroll
        for (int n = 0; n < 2; ++n)
          acc[m][n] = __builtin_amdgcn_mfma_f32_16x16x32_f16(afv, bf[n][s], acc[m][n], 0, 0, 0);
      }
    #pragma unroll
    for (int m = 0; m < 2; ++m)
      #pragma unroll
      for (int n = 0; n < 2; ++n) {
        const int col = w*32 + n*16 + fr;
        #pragma unroll
        for (int j = 0; j < 4; ++j) {
          const int row = m*16 + kg*4 + j;
          const size_t gi = (size_t)(b*LQ + t0 + row)*DM + col;
          hout[gi] = acc[m][n][j] + src[gi];
        }
      }
  }
}

// ---------------- final: last-token rmsnorm + batchnorm + relu + head ----------------
__global__ __launch_bounds__(256) void final_kernel(const float* __restrict__ h,
    const float* __restrict__ nfw, const float* __restrict__ gamma, const float* __restrict__ beta,
    const float* __restrict__ hw, const float* __restrict__ hb, float* __restrict__ out) {
  __shared__ float sf[8][128];
  __shared__ float sscale[8];
  int tid = threadIdx.x;
  for (int e = tid; e < 1024; e += 256) {
    int b = e >> 7, dd = e & 127;
    sf[b][dd] = h[((size_t)b*LQ + (LQ-1))*DM + dd];
  }
  __syncthreads();
  if (tid < 8) {
    float ss = 0.f;
    for (int dd = 0; dd < 128; ++dd) { float v = sf[tid][dd]; ss += v*v; }
    sscale[tid] = rsqrtf(ss/128.f + EPSF);
  }
  __syncthreads();
  for (int e = tid; e < 1024; e += 256) {
    int b = e >> 7, dd = e & 127;
    sf[b][dd] = sf[b][dd]*sscale[b]*nfw[dd];
  }
  __syncthreads();
  if (tid < 128) {
    float mu = 0.f;
    for (int b = 0; b < 8; ++b) mu += sf[b][tid];
    mu *= 0.125f;
    float var = 0.f;
    for (int b = 0; b < 8; ++b) { float dv = sf[b][tid]-mu; var += dv*dv; }
    var *= 0.125f;
    float rs = rsqrtf(var + EPSF);
    for (int b = 0; b < 8; ++b) {
      float v = (sf[b][tid]-mu)*rs*gamma[tid] + beta[tid];
      sf[b][tid] = v > 0.f ? v : 0.f;
    }
  }
  __syncthreads();
  if (tid < 16) {
    int b = tid >> 1, s = tid & 1;
    float acc = hb[s];
    for (int dd = 0; dd < 128; ++dd) acc += sf[b][dd]*hw[s*128+dd];
    out[b*2+s] = acc;
  }
}

extern "C" void kernel_launch(void* const* d_in, const int* in_sizes, int n_in,
                              void* d_out, int out_size, void* d_ws, size_t ws_size,
                              hipStream_t stream) {
  const float* x      = (const float*)d_in[0];
  const float* in_w   = (const float*)d_in[1];
  const float* conv_w = (const float*)d_in[2];
  const float* conv_b = (const float*)d_in[3];
  const float* xp_w   = (const float*)d_in[4];
  const float* dt_w   = (const float*)d_in[5];
  const float* dt_b   = (const float*)d_in[6];
  const float* A_log  = (const float*)d_in[7];
  const float* Dp     = (const float*)d_in[8];
  const float* out_w  = (const float*)d_in[9];
  const float* norm_w = (const float*)d_in[10];
  const float* norm_f = (const float*)d_in[11];
  const float* gamma  = (const float*)d_in[12];
  const float* beta   = (const float*)d_in[13];
  const float* head_w = (const float*)d_in[14];
  const float* head_b = (const float*)d_in[15];

  float* ws = (float*)d_ws;
  float* h     = ws;                             // ROWS*DM fp32
  float* dbc   = h + (size_t)ROWS*DM;            // ROWS*40 fp32
  float* S     = dbc + (size_t)ROWS*40;          // NB*NCHUNK*DI*16 fp32
  float* sumdl = S + (size_t)NB*NCHUNK*DI*16;    // NB*NCHUNK*DI fp32
  f16* xs     = (f16*)(sumdl + (size_t)NB*NCHUNK*DI); // ROWS*256 f16
  f16* wf_in  = xs + (size_t)ROWS*DI;                 // 4*512*128 f16
  f16* wf_xp  = wf_in + (size_t)4*2*DI*DM;            // 4*40*256 f16
  f16* wf_out = wf_xp + (size_t)4*40*DI;              // 4*128*256 f16

  cvt_all<<<424, 256, 0, stream>>>(in_w, xp_w, out_w, wf_in, wf_xp, wf_out);

  for (int layer = 0; layer < 4; ++layer) {
    const float* src = layer ? h : x;   // rmsnorm input and residual source
    layer_front<<<NB*NCHUNK, 256, 0, stream>>>(
        src, norm_w + (size_t)layer*DM, wf_in + (size_t)layer*2*DI*DM,
        conv_w + (size_t)layer*DI*4, conv_b + (size_t)layer*DI,
        wf_xp + (size_t)layer*40*DI, A_log + (size_t)layer*DI*DSN,
        dt_w + (size_t)layer*DI*8, dt_b + (size_t)layer*DI,
        xs, dbc, S, sumdl);
    layer_back<<<NB*NCHUNK, 256, 0, stream>>>(
        src, norm_w + (size_t)layer*DM, wf_in + (size_t)layer*2*DI*DM,
        xs, dbc, A_log + (size_t)layer*DI*DSN,
        dt_w + (size_t)layer*DI*8, dt_b + (size_t)layer*DI,
        Dp + (size_t)layer*DI, S, sumdl,
        wf_out + (size_t)layer*DM*DI, h);
  }
  final_kernel<<<1, 256, 0, stream>>>(h, norm_f, gamma, beta, head_w, head_b, (float*)d_out);
}